// Round 8
// baseline (85.575 us; speedup 1.0000x reference)
//
#include <hip/hip_runtime.h>
#include <math.h>

#define NB 2
#define NN 768
#define ND 64
#define XSTRIDE 68   // floats; 272 B rows: 16B-aligned writes, conflict-free reads

// barrier'd f32 ops: block FMA contraction / reassociation so rounding
// matches the numpy f32 reference bit-for-bit on sensitive chains
__device__ __forceinline__ float fmul_(float a, float b) { float r = a * b; asm volatile("" : "+v"(r)); return r; }
__device__ __forceinline__ float fadd_(float a, float b) { float r = a + b; asm volatile("" : "+v"(r)); return r; }

// numpy pairwise_sum for n=64 over a per-lane register array:
// 8 accumulators striding 8, then ((r0+r1)+(r2+r3)) + ((r4+r5)+(r6+r7))
template <typename F>
__device__ __forceinline__ float pw64(F f) {
  float r[8];
#pragma unroll
  for (int m = 0; m < 8; ++m) r[m] = f(m);
#pragma unroll
  for (int i = 1; i < 8; ++i) {
#pragma unroll
    for (int m = 0; m < 8; ++m) r[m] = fadd_(r[m], f(8 * i + m));
  }
  const float s01 = fadd_(r[0], r[1]), s23 = fadd_(r[2], r[3]);
  const float s45 = fadd_(r[4], r[5]), s67 = fadd_(r[6], r[7]);
  return fadd_(fadd_(s01, s23), fadd_(s45, s67));
}

// shuffle-based pairwise sum over lane-distributed values (lane k holds v_k).
// Bitwise-identical to pw64 (stage-1 same order; butterfly = balanced tree up
// to fp-add commutativity, which preserves rounding).
__device__ __forceinline__ float pwShfl(float v, int lane) {
  const int m = lane & 7;
  float s = __shfl(v, m);
#pragma unroll
  for (int i = 1; i < 8; ++i) s = fadd_(s, __shfl(v, m + 8 * i));
  s = fadd_(s, __shfl_xor(s, 1));
  s = fadd_(s, __shfl_xor(s, 2));
  s = fadd_(s, __shfl_xor(s, 4));
  return s;
}

// two independent pairwise sums, interleaved so the serial shuffle chains
// overlap; each result bitwise-identical to pwShfl of that input alone
__device__ __forceinline__ void pwShfl2(float va, float vb, int lane,
                                        float& sa, float& sb) {
  const int m = lane & 7;
  float a = __shfl(va, m), b = __shfl(vb, m);
#pragma unroll
  for (int i = 1; i < 8; ++i) {
    a = fadd_(a, __shfl(va, m + 8 * i));
    b = fadd_(b, __shfl(vb, m + 8 * i));
  }
  a = fadd_(a, __shfl_xor(a, 1)); b = fadd_(b, __shfl_xor(b, 1));
  a = fadd_(a, __shfl_xor(a, 2)); b = fadd_(b, __shfl_xor(b, 2));
  a = fadd_(a, __shfl_xor(a, 4)); b = fadd_(b, __shfl_xor(b, 4));
  sa = a; sb = b;
}

// correctly-rounded n/d given r = fl(1/d) (Markstein refinement; benign range)
__device__ __forceinline__ float div_rn(float n, float d, float r) {
  const float q0 = n * r;
  const float e  = __builtin_fmaf(-d, q0, n);
  return __builtin_fmaf(e, r, q0);
}

// FOUR waves per row (latency hiding): pairs striped p % 4 == wave. Phase A
// per-pair chain bitwise identical to rounds 4-7 (one lane per pair). Q/P
// combined across waves with a fixed ((w0+w1)+(w2+w3)) tree (1e-7-class
// reorder on validated-insensitive scalars). Epilogue on wave 0, verbatim.
__global__ __launch_bounds__(256) void k_main(const float* __restrict__ x,
                                              const float* __restrict__ adj,
                                              const float* __restrict__ attW,
                                              const float* __restrict__ attb,
                                              float* __restrict__ out) {
  __shared__ float xi_s[ND];
  __shared__ float sW2[ND];
  __shared__ short lj[NN];
  __shared__ float lds_x[64 * XSTRIDE];
  __shared__ float qs[4][4][ND];         // [wave][quarter][lane]
  __shared__ float sP[4];

  const int row  = blockIdx.x;           // 0..1535 = b*NN + i
  const int b    = row / NN;
  const int tid  = threadIdx.x;
  const int wv   = tid >> 6;             // 0..3
  const int lane = tid & 63;

  const float xiv = x[(size_t)row * ND + lane];   // same value in all waves
  if (wv == 0) { xi_s[lane] = xiv; sW2[lane] = attW[ND + lane]; }

  // all 4 waves load all adjacency chunks (redundant but unserialised)
  const float* __restrict__ arow = adj + (size_t)row * NN;
  float av[NN / 64];
#pragma unroll
  for (int c = 0; c < NN / 64; ++c) av[c] = arow[c * 64 + lane];

  // n_i with numpy-pairwise rounding (bitwise same as rounds 3-7)
  const float ni = pwShfl(fmul_(xiv, xiv), lane);

  const float b1  = 1.0f - ni;                       // Sterbenz: exact
  const float lam = 2.0f / fmaxf(b1, 1e-15f);        // ref rounding
  const float g1  = 2.0f / lam;                      // double-rounded "2/lam"
  const float ab  = attb[0];
  const float ATH_CLIP = (float)(1.0 - 1e-07);

  // ---- compact nonzero adj cols, ascending j; quarter bounds recorded.
  //      All 4 waves run the identical scan; lj writes race with identical
  //      values (benign). ----
  int count = 0, qb1 = 0, qb2 = 0, qb3 = 0;
#pragma unroll
  for (int c = 0; c < NN / 64; ++c) {
    const unsigned long long m = __ballot(av[c] != 0.0f);
    if (av[c] != 0.0f) {
      const int rank = __popcll(m & ((1ull << lane) - 1ull));
      lj[count + rank] = (short)(c * 64 + lane);
    }
    count += __popcll(m);                // wave-uniform
    if (c == 2) qb1 = count;             // end of j<192
    if (c == 5) qb2 = count;             // end of j<384
    if (c == 8) qb3 = count;             // end of j<576
  }
  __syncthreads();                       // covers xi_s, sW2, lj

  const float* __restrict__ xb = x + (size_t)b * NN * ND;
  float pP = 0.0f;
  float Q0 = 0.0f, Q1 = 0.0f, Q2 = 0.0f, Q3 = 0.0f;
  float cfv = 0.0f;                      // per-lane pair coeff (shfl source)

  for (int base = 0; base < count; base += 64) {
    const int valid = min(count - base, 64);
    const int slot  = 4 * lane + wv;     // this wave-lane's slot in the batch

    // ---- Phase A: per-pair chain (bitwise identical to rounds 4-7) ----
    if (slot < valid) {
      const int j = lj[base + slot];
      float rj[ND];
      const float4* __restrict__ xj4 = (const float4*)(xb + (size_t)j * ND);
#pragma unroll
      for (int k4 = 0; k4 < 16; ++k4) {
        const float4 v = xj4[k4];
        rj[4 * k4 + 0] = v.x; rj[4 * k4 + 1] = v.y;
        rj[4 * k4 + 2] = v.z; rj[4 * k4 + 3] = v.w;
      }
      // stage row into LDS for Phase B (values only; layout free)
      {
        float4* __restrict__ dst = (float4*)&lds_x[slot * XSTRIDE];
#pragma unroll
        for (int k4 = 0; k4 < 16; ++k4)
          dst[k4] = make_float4(rj[4 * k4], rj[4 * k4 + 1],
                                rj[4 * k4 + 2], rj[4 * k4 + 3]);
      }
      const float nj = pw64([&](int k) { return fmul_(rj[k], rj[k]); });
      const float d  = pw64([&](int k) { return fmul_(xi_s[k], rj[k]); });
      const float xy = -d;
      const float t1  = fadd_(1.0f, 2.0f * xy);      // 2*xy exact
      const float a1  = fadd_(t1, nj);               // 1 + 2c*xy + c*y2
      const float den = fadd_(t1, fmul_(ni, nj));    // 1 + 2c*xy + c^2*x2*y2
      const float denc = fmaxf(den, 1e-15f);
      const float rden = 1.0f / denc;
      float racc[8];
      float subW = 0.0f;
#pragma unroll
      for (int m = 0; m < 8; ++m) {
        const float nk = fadd_(-fmul_(a1, xi_s[m]), fmul_(b1, rj[m]));
        const float sk = div_rn(nk, denc, rden);
        subW = __builtin_fmaf(sk, sW2[m], subW);
        racc[m] = fmul_(sk, sk);
      }
#pragma unroll
      for (int i8 = 1; i8 < 8; ++i8) {
#pragma unroll
        for (int m = 0; m < 8; ++m) {
          const int k = 8 * i8 + m;
          const float nk = fadd_(-fmul_(a1, xi_s[k]), fmul_(b1, rj[k]));
          const float sk = div_rn(nk, denc, rden);
          subW = __builtin_fmaf(sk, sW2[k], subW);
          racc[m] = fadd_(racc[m], fmul_(sk, sk));
        }
      }
      const float s01 = fadd_(racc[0], racc[1]), s23 = fadd_(racc[2], racc[3]);
      const float s45 = fadd_(racc[4], racc[5]), s67 = fadd_(racc[6], racc[7]);
      const float s2  = fadd_(fadd_(s01, s23), fadd_(s45, s67));
      const float t   = sqrtf(s2);
      const float sn  = fmaxf(t, 1e-15f);            // sub_norm
      const float z   = fminf(sn, ATH_CLIP);
      const float ath = atanhf(z);
      const float g2  = fmul_(g1, ath);              // fl((2/lam)*artanh)
      const float gg  = g2 / sn;
      const float logit = gg * subW + ab;
      const float sig   = 1.0f / (1.0f + expf(-logit));
      const float cfac  = sig * gg * rden;           // att = sig*1.0 exactly
      cfv = cfac;
      pP = __builtin_fmaf(cfac, a1, pP);             // P partial: sum coeff*A
    }
    __syncthreads();

    // ---- Phase B: wave w accumulates its stripe s ≡ w (mod 4), ascending;
    //      quarter chosen by scalar wave-uniform compare on p = base+s ----
    for (int s = wv; s < valid; s += 4) {
      const float cf = __shfl(cfv, s >> 2);          // owner lane in this wave
      const float v  = lds_x[s * XSTRIDE + lane];    // conflict-free
      const int   p2 = base + s;                     // scalar
      if (p2 < qb1)      Q0 = __builtin_fmaf(cf, v, Q0);
      else if (p2 < qb2) Q1 = __builtin_fmaf(cf, v, Q1);
      else if (p2 < qb3) Q2 = __builtin_fmaf(cf, v, Q2);
      else               Q3 = __builtin_fmaf(cf, v, Q3);
    }
    __syncthreads();                                 // before re-staging
  }

  // per-wave P butterfly, then cross-wave combine via LDS
  float pw = pP;
#pragma unroll
  for (int m = 32; m >= 1; m >>= 1) pw += __shfl_xor(pw, m, 64);
  if (lane == 0) sP[wv] = pw;
  qs[wv][0][lane] = Q0; qs[wv][1][lane] = Q1;
  qs[wv][2][lane] = Q2; qs[wv][3][lane] = Q3;
  __syncthreads();

  if (wv == 0) {
    const float P = fadd_(fadd_(sP[0], sP[1]), fadd_(sP[2], sP[3]));
    const float q0 = fadd_(fadd_(qs[0][0][lane], qs[1][0][lane]),
                           fadd_(qs[2][0][lane], qs[3][0][lane]));
    const float q1 = fadd_(fadd_(qs[0][1][lane], qs[1][1][lane]),
                           fadd_(qs[2][1][lane], qs[3][1][lane]));
    const float q2 = fadd_(fadd_(qs[0][2][lane], qs[1][2][lane]),
                           fadd_(qs[2][2][lane], qs[3][2][lane]));
    const float q3 = fadd_(fadd_(qs[0][3][lane], qs[1][3][lane]),
                           fadd_(qs[2][3][lane], qs[3][3][lane]));
    const float Q = (q0 + q1) + (q2 + q3);

    // ---- epilogue: expmap + mobius + proj (verbatim from rounds 6/7) ----
    float u = b1 * Q - P * xiv;                      // support_t
    u = fminf(fmaxf(u, -1e6f), 1e6f);                // clip
    const float u2 = pwShfl(fmul_(u, u), lane);
    const float un = fmaxf(sqrtf(u2), 1e-15f);
    const float th = tanhf(fmul_(0.5f * lam, un));   // 0.5*lam exact
    const float sec = fmul_(th, u) / un;             // second_d
    float y2, xys;
    pwShfl2(fmul_(sec, sec), fmul_(xiv, sec), lane, y2, xys);
    const float t1e  = fadd_(1.0f, 2.0f * xys);
    const float a1e  = fadd_(t1e, y2);
    const float dene = fmaxf(fadd_(t1e, fmul_(ni, y2)), 1e-15f);
    const float o    = fadd_(fmul_(a1e, xiv), fmul_(b1, sec)) / dene;
    const float o2 = pwShfl(fmul_(o, o), lane);
    const float nm = fmaxf(sqrtf(o2), 1e-15f);
    const float res = (nm > 0.996f) ? fmul_(o / nm, 0.996f) : o;
    out[(size_t)row * ND + lane] = res;
  }
}

extern "C" void kernel_launch(void* const* d_in, const int* in_sizes, int n_in,
                              void* d_out, int out_size, void* d_ws, size_t ws_size,
                              hipStream_t stream) {
  const float* x    = (const float*)d_in[0];
  const float* adj  = (const float*)d_in[1];
  const float* attW = (const float*)d_in[2];
  const float* attb = (const float*)d_in[3];
  float* out = (float*)d_out;

  hipLaunchKernelGGL(k_main, dim3(NB * NN), dim3(256), 0, stream,
                     x, adj, attW, attb, out);
}

// Round 9
// 74.908 us; speedup vs baseline: 1.1424x; 1.1424x over previous
//
#include <hip/hip_runtime.h>
#include <math.h>

#define NB 2
#define NN 768
#define ND 64
#define XSTRIDE 68   // floats; 272 B rows: 16B-aligned writes, conflict-free reads

// barrier'd f32 ops: block FMA contraction / reassociation so rounding
// matches the numpy f32 reference bit-for-bit on sensitive chains
__device__ __forceinline__ float fmul_(float a, float b) { float r = a * b; asm volatile("" : "+v"(r)); return r; }
__device__ __forceinline__ float fadd_(float a, float b) { float r = a + b; asm volatile("" : "+v"(r)); return r; }

// numpy pairwise_sum for n=64 over a per-lane register array:
// 8 accumulators striding 8, then ((r0+r1)+(r2+r3)) + ((r4+r5)+(r6+r7))
template <typename F>
__device__ __forceinline__ float pw64(F f) {
  float r[8];
#pragma unroll
  for (int m = 0; m < 8; ++m) r[m] = f(m);
#pragma unroll
  for (int i = 1; i < 8; ++i) {
#pragma unroll
    for (int m = 0; m < 8; ++m) r[m] = fadd_(r[m], f(8 * i + m));
  }
  const float s01 = fadd_(r[0], r[1]), s23 = fadd_(r[2], r[3]);
  const float s45 = fadd_(r[4], r[5]), s67 = fadd_(r[6], r[7]);
  return fadd_(fadd_(s01, s23), fadd_(s45, s67));
}

// two independent pw64 sums with interleaved chains (overlaps the serial add
// trees); each result bitwise-identical to pw64 of that input alone
template <typename F, typename G>
__device__ __forceinline__ void pw64x2(F f, G g, float& sf, float& sg) {
  float r[8], q[8];
#pragma unroll
  for (int m = 0; m < 8; ++m) { r[m] = f(m); q[m] = g(m); }
#pragma unroll
  for (int i = 1; i < 8; ++i) {
#pragma unroll
    for (int m = 0; m < 8; ++m) {
      r[m] = fadd_(r[m], f(8 * i + m));
      q[m] = fadd_(q[m], g(8 * i + m));
    }
  }
  const float a01 = fadd_(r[0], r[1]), a23 = fadd_(r[2], r[3]);
  const float a45 = fadd_(r[4], r[5]), a67 = fadd_(r[6], r[7]);
  const float b01 = fadd_(q[0], q[1]), b23 = fadd_(q[2], q[3]);
  const float b45 = fadd_(q[4], q[5]), b67 = fadd_(q[6], q[7]);
  sf = fadd_(fadd_(a01, a23), fadd_(a45, a67));
  sg = fadd_(fadd_(b01, b23), fadd_(b45, b67));
}

// shuffle-based pairwise sum over lane-distributed values (lane k holds v_k).
// Bitwise-identical to pw64 (stage-1 same order; butterfly = balanced tree up
// to fp-add commutativity, which preserves rounding).
__device__ __forceinline__ float pwShfl(float v, int lane) {
  const int m = lane & 7;
  float s = __shfl(v, m);
#pragma unroll
  for (int i = 1; i < 8; ++i) s = fadd_(s, __shfl(v, m + 8 * i));
  s = fadd_(s, __shfl_xor(s, 1));
  s = fadd_(s, __shfl_xor(s, 2));
  s = fadd_(s, __shfl_xor(s, 4));
  return s;
}

// two independent pairwise sums, interleaved so the serial shuffle chains
// overlap; each result bitwise-identical to pwShfl of that input alone
__device__ __forceinline__ void pwShfl2(float va, float vb, int lane,
                                        float& sa, float& sb) {
  const int m = lane & 7;
  float a = __shfl(va, m), b = __shfl(vb, m);
#pragma unroll
  for (int i = 1; i < 8; ++i) {
    a = fadd_(a, __shfl(va, m + 8 * i));
    b = fadd_(b, __shfl(vb, m + 8 * i));
  }
  a = fadd_(a, __shfl_xor(a, 1)); b = fadd_(b, __shfl_xor(b, 1));
  a = fadd_(a, __shfl_xor(a, 2)); b = fadd_(b, __shfl_xor(b, 2));
  a = fadd_(a, __shfl_xor(a, 4)); b = fadd_(b, __shfl_xor(b, 4));
  sa = a; sb = b;
}

// correctly-rounded n/d given r = fl(1/d) (Markstein refinement; benign range)
__device__ __forceinline__ float div_rn(float n, float d, float r) {
  const float q0 = n * r;
  const float e  = __builtin_fmaf(-d, q0, n);
  return __builtin_fmaf(e, r, q0);
}

// One wave per row (round-7 structure). Ballot-compact nonzero adj cols with
// quarter boundaries; bit-faithful per-pair chain; Phase B = four tight
// per-quarter loops. Serial-path micro-cuts: adj loads issued first, nj/d
// trees interleaved, subW in 2 chains (insensitive path).
__global__ __launch_bounds__(64) void k_main(const float* __restrict__ x,
                                             const float* __restrict__ adj,
                                             const float* __restrict__ attW,
                                             const float* __restrict__ attb,
                                             float* __restrict__ out) {
  __shared__ float xi_s[ND];
  __shared__ float sW2[ND];
  __shared__ short lj[NN];
  __shared__ float lds_x[64 * XSTRIDE];

  const int row  = blockIdx.x;           // 0..1535 = b*NN + i
  const int b    = row / NN;
  const int lane = threadIdx.x;          // 0..63

  // adjacency chunk loads first: longest-latency (HBM-cold) on the scan path
  const float* __restrict__ arow = adj + (size_t)row * NN;
  float av[NN / 64];
#pragma unroll
  for (int c = 0; c < NN / 64; ++c) av[c] = arow[c * 64 + lane];

  const float xiv = x[(size_t)row * ND + lane];
  xi_s[lane] = xiv;
  sW2[lane]  = attW[ND + lane];

  // n_i with numpy-pairwise rounding (bitwise same as rounds 3-7)
  const float ni = pwShfl(fmul_(xiv, xiv), lane);

  const float b1  = 1.0f - ni;                       // Sterbenz: exact
  const float lam = 2.0f / fmaxf(b1, 1e-15f);        // ref rounding
  const float g1  = 2.0f / lam;                      // double-rounded "2/lam"
  const float ab  = attb[0];
  const float ATH_CLIP = (float)(1.0 - 1e-07);

  // ---- compact nonzero adj columns, ascending j; record quarter bounds ----
  int count = 0, qb1 = 0, qb2 = 0, qb3 = 0;
#pragma unroll
  for (int c = 0; c < NN / 64; ++c) {
    const unsigned long long m = __ballot(av[c] != 0.0f);
    if (av[c] != 0.0f) {
      const int rank = __popcll(m & ((1ull << lane) - 1ull));
      lj[count + rank] = (short)(c * 64 + lane);
    }
    count += __popcll(m);                // wave-uniform
    if (c == 2) qb1 = count;             // end of j<192
    if (c == 5) qb2 = count;             // end of j<384
    if (c == 8) qb3 = count;             // end of j<576
  }
  __syncthreads();

  const float* __restrict__ xb = x + (size_t)b * NN * ND;
  float pP = 0.0f;
  float Q0 = 0.0f, Q1 = 0.0f, Q2 = 0.0f, Q3 = 0.0f;
  float cfv = 0.0f;                      // per-lane pair coeff (shfl source)

  for (int base = 0; base < count; base += 64) {
    const int valid = min(count - base, 64);

    // ---- Phase A: per-pair chain (bitwise identical to rounds 4-7) ----
    if (lane < valid) {
      const int j = lj[base + lane];
      float rj[ND];
      const float4* __restrict__ xj4 = (const float4*)(xb + (size_t)j * ND);
#pragma unroll
      for (int k4 = 0; k4 < 16; ++k4) {
        const float4 v = xj4[k4];
        rj[4 * k4 + 0] = v.x; rj[4 * k4 + 1] = v.y;
        rj[4 * k4 + 2] = v.z; rj[4 * k4 + 3] = v.w;
      }
      // stage row into LDS for Phase B (values only; layout free)
      {
        float4* __restrict__ dst = (float4*)&lds_x[lane * XSTRIDE];
#pragma unroll
        for (int k4 = 0; k4 < 16; ++k4)
          dst[k4] = make_float4(rj[4 * k4], rj[4 * k4 + 1],
                                rj[4 * k4 + 2], rj[4 * k4 + 3]);
      }
      // nj and d: interleaved trees, each bitwise = pw64 of that input
      float nj, d;
      pw64x2([&](int k) { return fmul_(rj[k], rj[k]); },
             [&](int k) { return fmul_(xi_s[k], rj[k]); }, nj, d);
      const float xy = -d;
      const float t1  = fadd_(1.0f, 2.0f * xy);      // 2*xy exact
      const float a1  = fadd_(t1, nj);               // 1 + 2c*xy + c*y2
      const float den = fadd_(t1, fmul_(ni, nj));    // 1 + 2c*xy + c^2*x2*y2
      const float denc = fmaxf(den, 1e-15f);
      const float rden = 1.0f / denc;                // correctly rounded seed
      float racc[8];
      float subW0 = 0.0f, subW1 = 0.0f;              // 2 chains (insens. path)
#pragma unroll
      for (int m = 0; m < 8; ++m) {
        const float nk = fadd_(-fmul_(a1, xi_s[m]), fmul_(b1, rj[m]));
        const float sk = div_rn(nk, denc, rden);
        if (m & 1) subW1 = __builtin_fmaf(sk, sW2[m], subW1);
        else       subW0 = __builtin_fmaf(sk, sW2[m], subW0);
        racc[m] = fmul_(sk, sk);
      }
#pragma unroll
      for (int i8 = 1; i8 < 8; ++i8) {
#pragma unroll
        for (int m = 0; m < 8; ++m) {
          const int k = 8 * i8 + m;
          const float nk = fadd_(-fmul_(a1, xi_s[k]), fmul_(b1, rj[k]));
          const float sk = div_rn(nk, denc, rden);
          if (m & 1) subW1 = __builtin_fmaf(sk, sW2[k], subW1);
          else       subW0 = __builtin_fmaf(sk, sW2[k], subW0);
          racc[m] = fadd_(racc[m], fmul_(sk, sk));
        }
      }
      const float subW = subW0 + subW1;
      const float s01 = fadd_(racc[0], racc[1]), s23 = fadd_(racc[2], racc[3]);
      const float s45 = fadd_(racc[4], racc[5]), s67 = fadd_(racc[6], racc[7]);
      const float s2  = fadd_(fadd_(s01, s23), fadd_(s45, s67));
      const float t   = sqrtf(s2);
      const float sn  = fmaxf(t, 1e-15f);            // sub_norm
      const float z   = fminf(sn, ATH_CLIP);
      const float ath = atanhf(z);
      const float g2  = fmul_(g1, ath);              // fl((2/lam)*artanh)
      const float gg  = g2 / sn;
      const float logit = gg * subW + ab;
      const float sig   = 1.0f / (1.0f + expf(-logit));
      const float cfac  = sig * gg * rden;           // att = sig*1.0 exactly
      cfv = cfac;
      pP = __builtin_fmaf(cfac, a1, pP);             // P = sum coeff*A
    }
    __syncthreads();

    // ---- Phase B: four tight per-quarter loops (quarters contiguous in p;
    //      accumulation order within each Qq = ascending p, bitwise as before)
    const int lim = base + valid;
    {
      const int lo = max(0,   base), hi = min(qb1, lim);
#pragma unroll 2
      for (int p2 = lo; p2 < hi; ++p2)
        Q0 = __builtin_fmaf(__shfl(cfv, p2 - base),
                            lds_x[(p2 - base) * XSTRIDE + lane], Q0);
    }
    {
      const int lo = max(qb1, base), hi = min(qb2, lim);
#pragma unroll 2
      for (int p2 = lo; p2 < hi; ++p2)
        Q1 = __builtin_fmaf(__shfl(cfv, p2 - base),
                            lds_x[(p2 - base) * XSTRIDE + lane], Q1);
    }
    {
      const int lo = max(qb2, base), hi = min(qb3, lim);
#pragma unroll 2
      for (int p2 = lo; p2 < hi; ++p2)
        Q2 = __builtin_fmaf(__shfl(cfv, p2 - base),
                            lds_x[(p2 - base) * XSTRIDE + lane], Q2);
    }
    {
      const int lo = max(qb3, base), hi = min(count, lim);
#pragma unroll 2
      for (int p2 = lo; p2 < hi; ++p2)
        Q3 = __builtin_fmaf(__shfl(cfv, p2 - base),
                            lds_x[(p2 - base) * XSTRIDE + lane], Q3);
    }
    __syncthreads();                                 // before re-staging
  }

  // wave-reduce P (scalar; reorder noise ~1e-7, not amplified)
  float pw = pP;
#pragma unroll
  for (int m = 32; m >= 1; m >>= 1) pw += __shfl_xor(pw, m, 64);
  const float P = pw;
  const float Q = (Q0 + Q1) + (Q2 + Q3);

  // ---- epilogue: expmap + mobius + proj (verbatim from rounds 6/7) ----
  float u = b1 * Q - P * xiv;                        // support_t
  u = fminf(fmaxf(u, -1e6f), 1e6f);                  // clip
  const float u2 = pwShfl(fmul_(u, u), lane);
  const float un = fmaxf(sqrtf(u2), 1e-15f);
  const float th = tanhf(fmul_(0.5f * lam, un));     // 0.5*lam exact
  const float sec = fmul_(th, u) / un;               // second_d
  float y2, xys;
  pwShfl2(fmul_(sec, sec), fmul_(xiv, sec), lane, y2, xys);
  const float t1e  = fadd_(1.0f, 2.0f * xys);
  const float a1e  = fadd_(t1e, y2);
  const float dene = fmaxf(fadd_(t1e, fmul_(ni, y2)), 1e-15f);
  const float o    = fadd_(fmul_(a1e, xiv), fmul_(b1, sec)) / dene;
  const float o2 = pwShfl(fmul_(o, o), lane);
  const float nm = fmaxf(sqrtf(o2), 1e-15f);
  const float res = (nm > 0.996f) ? fmul_(o / nm, 0.996f) : o;
  out[(size_t)row * ND + lane] = res;
}

extern "C" void kernel_launch(void* const* d_in, const int* in_sizes, int n_in,
                              void* d_out, int out_size, void* d_ws, size_t ws_size,
                              hipStream_t stream) {
  const float* x    = (const float*)d_in[0];
  const float* adj  = (const float*)d_in[1];
  const float* attW = (const float*)d_in[2];
  const float* attb = (const float*)d_in[3];
  float* out = (float*)d_out;

  hipLaunchKernelGGL(k_main, dim3(NB * NN), dim3(64), 0, stream,
                     x, adj, attW, attb, out);
}